// Round 4
// baseline (324.859 us; speedup 1.0000x reference)
//
#include <hip/hip_runtime.h>
#include <hip/hip_fp16.h>

#define NB 2
#define NPTS 8192
#define NQ 4096
#define MTOT 8192      // NB*NQ
#define SP 16
#define SD 32
#define CIN 32
#define CP 32
#define CF 64
#define NROI 128       // NB*64
#define RADIUS_C 0.8f
#define MIN_R_C 0.01f
#define DIV_COEF_C 10.0f

// ---- spatial grid (cell = radius = 0.8; scene = [10,10,4]) ----------------
#define INV_CS 1.25f
#define NCX 13
#define NCY 13
#define NCZ 5
#define NCELL (NCX * NCY * NCZ)   // 845

// ---------------- device-global scratch (fully rewritten every call) -------
__device__ int   g_idx_p[MTOT * SP];
__device__ int   g_empty_p[MTOT];
__device__ int   g_idx_d[MTOT * SD];
__device__ int   g_empty_d[MTOT];
__device__ int   g_cellcnt[NB][NCELL];
__device__ int   g_cellcur[NB][NCELL];
__device__ int   g_cellstart[NB][NCELL + 1];
__device__ int   g_cellpts[NB][NPTS];
__device__ int   g_ptcell[NB][NPTS];
// generic activation buffers: p-branch uses fp32 (16.7MB), f-branch fp16 (33.5MB)
__device__ unsigned char g_xa[(size_t)MTOT * SD * CF * 2];
__device__ unsigned char g_xb[(size_t)MTOT * SD * CF * 2];
__device__ float g_psT[CF * 2048];                // transposed: [ch][block]
__device__ float g_pqT[CF * 2048];
__device__ float g_bnscale[4][CF];                // 0=p0 1=p1 2=f0 3=f1
__device__ float g_bnshift[4][CF];
__device__ float g_pdot[MTOT];
__device__ float g_rroi[NROI];

// ---------------- new_xyz output is rois flattened -------------------------
__global__ void copy_xyz_kernel(const float* __restrict__ rois, float* __restrict__ out) {
    int i = blockIdx.x * 256 + threadIdx.x;
    if (i < MTOT * 3) out[i] = rois[i];
}

// ================= grid build (shared by both bq calls) =====================
__global__ void grid_zero_kernel() {
    int i = blockIdx.x * 1024 + threadIdx.x;
    if (i < NB * NCELL) ((int*)g_cellcnt)[i] = 0;
}

__device__ __forceinline__ int cell_of(float x, float y, float z) {
    int cx = min(NCX - 1, max(0, (int)floorf(x * INV_CS)));
    int cy = min(NCY - 1, max(0, (int)floorf(y * INV_CS)));
    int cz = min(NCZ - 1, max(0, (int)floorf(z * INV_CS)));
    return (cz * NCY + cy) * NCX + cx;
}

__global__ void grid_count_kernel(const float* __restrict__ xyz) {
    int i = blockIdx.x * 256 + threadIdx.x;   // 0..16383
    int b = i >> 13, il = i & (NPTS - 1);
    int cell = cell_of(xyz[(size_t)i * 3 + 0], xyz[(size_t)i * 3 + 1], xyz[(size_t)i * 3 + 2]);
    g_ptcell[b][il] = cell;
    atomicAdd(&g_cellcnt[b][cell], 1);
}

__global__ void grid_prefix_kernel() {
    __shared__ int sc[1024];
    int tid = threadIdx.x;
    for (int b = 0; b < NB; ++b) {
        int v = (tid < NCELL) ? g_cellcnt[b][tid] : 0;
        __syncthreads();
        sc[tid] = v;
        __syncthreads();
        for (int off = 1; off < 1024; off <<= 1) {
            int add = (tid >= off) ? sc[tid - off] : 0;
            __syncthreads();
            sc[tid] += add;
            __syncthreads();
        }
        if (tid < NCELL) {
            int excl = sc[tid] - v;
            g_cellstart[b][tid] = excl;
            g_cellcur[b][tid] = excl;
        }
        if (tid == 0) g_cellstart[b][NCELL] = NPTS;
    }
}

__global__ void grid_scatter_kernel() {
    int i = blockIdx.x * 256 + threadIdx.x;
    int b = i >> 13, il = i & (NPTS - 1);
    int cell = g_ptcell[b][il];
    int pos = atomicAdd(&g_cellcur[b][cell], 1);
    g_cellpts[b][pos] = il;
}

__global__ void grid_sort_kernel() {   // per-cell ascending index sort (tiny lists)
    int c = blockIdx.x * 256 + threadIdx.x;
    if (c >= NB * NCELL) return;
    int b = c / NCELL, cell = c % NCELL;
    int s = g_cellstart[b][cell], e = g_cellstart[b][cell + 1];
    for (int i = s + 1; i < e; ++i) {
        int v = g_cellpts[b][i];
        int j = i - 1;
        while (j >= s && g_cellpts[b][j] > v) { g_cellpts[b][j + 1] = g_cellpts[b][j]; --j; }
        g_cellpts[b][j + 1] = v;
    }
}

// ======= ball query via grid: one wave per query, per-wave bitonic select ===
// NS smallest in-radius point indices == "first NS found in index order".
template <int NS>
__launch_bounds__(256, 8)
__global__ void bq_grid_kernel(const float* __restrict__ xyz, const float* __restrict__ newxyz) {
    __shared__ int s_cand[4][256];
    __shared__ int s_cs[4][64];
    __shared__ int s_pre[4][64];
    int tid = threadIdx.x, wv = tid >> 6, lane = tid & 63;
    int q = blockIdx.x * 4 + wv;
    int b = q >> 12;
    float qx = newxyz[q * 3 + 0], qy = newxyz[q * 3 + 1], qz = newxyz[q * 3 + 2];
    float r = (NS == SP) ? RADIUS_C : g_rroi[q >> 6];
    float r2 = r * r;
    int* idx_out   = (NS == SP) ? g_idx_p   : g_idx_d;
    int* empty_out = (NS == SP) ? g_empty_p : g_empty_d;
    const float* xb = xyz + (size_t)b * NPTS * 3;

    float rp = r + 1e-4f;                 // cell-range padding (fp safety)
    int xlo = max(0, min(NCX - 1, (int)floorf((qx - rp) * INV_CS)));
    int xhi = max(0, min(NCX - 1, (int)floorf((qx + rp) * INV_CS)));
    int ylo = max(0, min(NCY - 1, (int)floorf((qy - rp) * INV_CS)));
    int yhi = max(0, min(NCY - 1, (int)floorf((qy + rp) * INV_CS)));
    int zlo = max(0, min(NCZ - 1, (int)floorf((qz - rp) * INV_CS)));
    int zhi = max(0, min(NCZ - 1, (int)floorf((qz + rp) * INV_CS)));
    int nx = xhi - xlo + 1, ny = yhi - ylo + 1, nz = zhi - zlo + 1;
    int ncell = nx * ny * nz;

    int cnt = 0;
    bool fallback = (ncell > 64);
    if (!fallback) {
        // lane -> one candidate cell; wave prefix-sum of cell sizes
        int cstart = 0, ccnt = 0;
        if (lane < ncell) {
            int cx = xlo + (lane % nx);
            int t1 = lane / nx;
            int cy = ylo + (t1 % ny);
            int cz = zlo + (t1 / ny);
            int cell = (cz * NCY + cy) * NCX + cx;
            cstart = g_cellstart[b][cell];
            ccnt = g_cellstart[b][cell + 1] - cstart;
        }
        int incl = ccnt;
#pragma unroll
        for (int off = 1; off < 64; off <<= 1) {
            int n = __shfl_up(incl, off, 64);
            if (lane >= off) incl += n;
        }
        int T = __shfl(incl, 63, 64);
        s_cs[wv][lane] = cstart;
        s_pre[wv][lane] = incl - ccnt;
        __asm__ volatile("s_waitcnt lgkmcnt(0)" ::: "memory");
        // gather: lanes sweep the concatenated candidate entries
        for (int t0 = 0; t0 < T; t0 += 64) {
            int t = t0 + lane;
            int p = -1;
            float d2 = 1e30f;
            if (t < T) {
                int lo = 0, hi = ncell - 1;
                while (lo < hi) { int mid = (lo + hi + 1) >> 1; if (s_pre[wv][mid] <= t) lo = mid; else hi = mid - 1; }
                int e = s_cs[wv][lo] + (t - s_pre[wv][lo]);
                p = g_cellpts[b][e];
                float dx = qx - xb[3 * p + 0];
                float dy = qy - xb[3 * p + 1];
                float dz = qz - xb[3 * p + 2];
                d2 = dx * dx + dy * dy + dz * dz;
            }
            bool valid = (t < T) && (d2 < r2);
            unsigned long long mask = __ballot(valid);
            int pos = cnt + __popcll(mask & ((1ull << lane) - 1ull));
            if (valid && pos < 256) s_cand[wv][pos] = p;
            cnt += (int)__popcll(mask);
        }
        if (cnt > 256) fallback = true;
    }
    if (fallback) {   // rare: huge radius or >256 in-ball — original ordered scan
        int cnt2 = 0, first_idx = 0;
        for (int g = 0; g < NPTS / 64 && cnt2 < NS; ++g) {
            int p = (g << 6) + lane;
            float dx = qx - xb[3 * p + 0];
            float dy = qy - xb[3 * p + 1];
            float dz = qz - xb[3 * p + 2];
            bool valid = (dx * dx + dy * dy + dz * dz) < r2;
            unsigned long long mask = __ballot(valid);
            if (cnt2 == 0 && mask) first_idx = (g << 6) + (int)__builtin_ctzll(mask);
            int pos = cnt2 + __popcll(mask & ((1ull << lane) - 1ull));
            if (valid && pos < NS) idx_out[q * NS + pos] = p;
            cnt2 += (int)__popcll(mask);
        }
        if (cnt2 == 0) {
            if (lane < NS) idx_out[q * NS + lane] = 0;
            if (lane == 0) empty_out[q] = 1;
        } else {
            int filled = cnt2 < NS ? cnt2 : NS;
            if (lane >= filled && lane < NS) idx_out[q * NS + lane] = first_idx;
            if (lane == 0) empty_out[q] = 0;
        }
        return;
    }
    if (cnt == 0) {
        if (lane < NS) idx_out[q * NS + lane] = 0;
        if (lane == 0) empty_out[q] = 1;
        return;
    }
    // per-wave bitonic sort of candidates (pad to pow2 with INT_MAX)
    int S = 64; while (S < cnt) S <<= 1;
    for (int i = cnt + lane; i < S; i += 64) s_cand[wv][i] = 0x7FFFFFFF;
    __asm__ volatile("s_waitcnt lgkmcnt(0)" ::: "memory");
    for (int k = 2; k <= S; k <<= 1) {
        for (int jj = k >> 1; jj > 0; jj >>= 1) {
            for (int i = lane; i < S; i += 64) {
                int l = i ^ jj;
                if (l > i) {
                    int a = s_cand[wv][i], c2 = s_cand[wv][l];
                    bool up = ((i & k) == 0);
                    if (up ? (a > c2) : (a < c2)) { s_cand[wv][i] = c2; s_cand[wv][l] = a; }
                }
            }
            __asm__ volatile("s_waitcnt lgkmcnt(0)" ::: "memory");
        }
    }
    int first = s_cand[wv][0];
    if (lane < NS) idx_out[q * NS + lane] = (lane < cnt) ? s_cand[wv][lane] : first;
    if (lane == 0) empty_out[q] = 0;
}

// ============ 3-pass MLP =====================================================
// PASS A: gather -> L0 -> store x0 (fp32 for p-branch, fp16 for f-branch) + stats
// block = 128 threads (2 waves), LDS <= 19.5 KB.
template <int NS, int CH, bool HALF>
__launch_bounds__(128, 4)
__global__ void mlp_passA_kernel(const float* __restrict__ xyz, const float* __restrict__ feats,
                                 const float* __restrict__ newxyz, const float* __restrict__ W0,
                                 void* __restrict__ xout_) {
    constexpr int GSTR = 37;        // gather row stride (35 used)
    constexpr int SST  = CH + 2;    // stats/store transpose stride
    __shared__ float buf[128 * GSTR];
    __shared__ float ls[128], lq[128];
    int tid = threadIdx.x;
    int rowbase = blockIdx.x * 128;
    int row = rowbase + tid;
    int q = row / NS, b = q >> 12;
    const int* idx_arr = (NS == SP) ? g_idx_p : g_idx_d;
    const int* emp_arr = (NS == SP) ? g_empty_p : g_empty_d;
    {
        float* dst = &buf[tid * GSTR];
        if (emp_arr[q]) {
#pragma unroll
            for (int c = 0; c < 35; ++c) dst[c] = 0.f;
        } else {
            int idx = idx_arr[row];
            const float* xp = xyz + (size_t)b * NPTS * 3 + idx * 3;
            dst[0] = xp[0] - newxyz[q * 3 + 0];
            dst[1] = xp[1] - newxyz[q * 3 + 1];
            dst[2] = xp[2] - newxyz[q * 3 + 2];
            const float4* fp = (const float4*)(feats + (size_t)b * NPTS * CIN + (size_t)idx * CIN);
#pragma unroll
            for (int j = 0; j < 8; ++j) {
                float4 v = fp[j];
                dst[3 + 4 * j + 0] = v.x; dst[3 + 4 * j + 1] = v.y;
                dst[3 + 4 * j + 2] = v.z; dst[3 + 4 * j + 3] = v.w;
            }
        }
    }
    // L0 from own LDS row (no barrier needed)
    float acc[CH];
#pragma unroll
    for (int ch = 0; ch < CH; ++ch) acc[ch] = 0.f;
    {
        const float* inrow = &buf[tid * GSTR];
        for (int c = 0; c < 35; ++c) {
            float h = inrow[c];
#pragma unroll
            for (int ch = 0; ch < CH; ++ch) acc[ch] = fmaf(h, W0[c * CH + ch], acc[ch]);
        }
    }
    // stats (fp32, pre-rounding) + coalesced store via chunked LDS transpose
    float* xf = (float*)xout_;
    __half* xh = (__half*)xout_;
    float sum = 0.f, sq = 0.f;
#pragma unroll
    for (int p = 0; p < 2; ++p) {
        __syncthreads();
        if ((tid >> 6) == p) {
            float* srow = &buf[(tid & 63) * SST];
#pragma unroll
            for (int ch = 0; ch < CH; ++ch) srow[ch] = acc[ch];
        }
        __syncthreads();
        if (CH == 64) {
            int ch = tid & 63, rg = tid >> 6;
            for (int r = 0; r < 32; ++r) {
                float v = buf[(rg * 32 + r) * SST + ch];
                size_t o = (size_t)(rowbase + p * 64 + rg * 32 + r) * CH + ch;
                if (HALF) xh[o] = __float2half_rn(v); else xf[o] = v;
                sum += v; sq += v * v;
            }
        } else {
            int ch = tid & 31, rg = tid >> 5;
            for (int r = 0; r < 16; ++r) {
                float v = buf[(rg * 16 + r) * SST + ch];
                size_t o = (size_t)(rowbase + p * 64 + rg * 16 + r) * CH + ch;
                if (HALF) xh[o] = __float2half_rn(v); else xf[o] = v;
                sum += v; sq += v * v;
            }
        }
    }
    ls[tid] = sum; lq[tid] = sq;
    __syncthreads();
    if (CH == 64) {
        if (tid < 64) {
            g_psT[tid * 2048 + blockIdx.x] = ls[tid] + ls[64 + tid];
            g_pqT[tid * 2048 + blockIdx.x] = lq[tid] + lq[64 + tid];
        }
    } else {
        if (tid < 32) {
            g_psT[tid * 2048 + blockIdx.x] = ls[tid] + ls[32 + tid] + ls[64 + tid] + ls[96 + tid];
            g_pqT[tid * 2048 + blockIdx.x] = lq[tid] + lq[32 + tid] + lq[64 + tid] + lq[96 + tid];
        }
    }
}

// PASS B (p-branch, fp32): stream x0p -> BN0+ReLU -> L1 -> store x1p + stats
template <int NS, int CH>
__launch_bounds__(128, 4)
__global__ void mlp_passB_kernel(const float* __restrict__ W1, const float* __restrict__ xin,
                                 float* __restrict__ xout, int bn0) {
    constexpr int HSTR = 33;
    constexpr int SST  = CH + 2;
    __shared__ float buf[128 * 37];
    __shared__ float ls[128], lq[128];
    int tid = threadIdx.x;
    int rowbase = blockIdx.x * 128;
    const float* sc0 = g_bnscale[bn0];
    const float* sh0 = g_bnshift[bn0];
    float acc2[CH];
#pragma unroll
    for (int ch = 0; ch < CH; ++ch) acc2[ch] = 0.f;
    const float4* src = (const float4*)xin;
#pragma unroll
    for (int hc = 0; hc < CH / 32; ++hc) {
        if (hc) __syncthreads();
#pragma unroll
        for (int k = 0; k < 8; ++k) {
            int o4 = tid + k * 128;       // 0..1023
            int rloc = o4 >> 3, j = o4 & 7;
            int c = 4 * j, gc = hc * 32 + c;
            float4 v = src[(size_t)(rowbase + rloc) * (CH / 4) + hc * 8 + j];
            float* d = &buf[rloc * HSTR + c];
            d[0] = fmaxf(fmaf(v.x, sc0[gc + 0], sh0[gc + 0]), 0.f);
            d[1] = fmaxf(fmaf(v.y, sc0[gc + 1], sh0[gc + 1]), 0.f);
            d[2] = fmaxf(fmaf(v.z, sc0[gc + 2], sh0[gc + 2]), 0.f);
            d[3] = fmaxf(fmaf(v.w, sc0[gc + 3], sh0[gc + 3]), 0.f);
        }
        __syncthreads();
        const float* hrow = &buf[tid * HSTR];
        for (int c = 0; c < 32; ++c) {
            float h = hrow[c];
#pragma unroll
            for (int ch = 0; ch < CH; ++ch)
                acc2[ch] = fmaf(h, W1[(hc * 32 + c) * CH + ch], acc2[ch]);
        }
    }
    float sum = 0.f, sq = 0.f;
#pragma unroll
    for (int p = 0; p < 2; ++p) {
        __syncthreads();
        if ((tid >> 6) == p) {
            float* srow = &buf[(tid & 63) * SST];
#pragma unroll
            for (int ch = 0; ch < CH; ++ch) srow[ch] = acc2[ch];
        }
        __syncthreads();
        int ch = tid & 31, rg = tid >> 5;
        for (int r = 0; r < 16; ++r) {
            float v = buf[(rg * 16 + r) * SST + ch];
            xout[(size_t)(rowbase + p * 64 + rg * 16 + r) * CH + ch] = v;
            sum += v; sq += v * v;
        }
    }
    ls[tid] = sum; lq[tid] = sq;
    __syncthreads();
    if (tid < 32) {
        g_psT[tid * 2048 + blockIdx.x] = ls[tid] + ls[32 + tid] + ls[64 + tid] + ls[96 + tid];
        g_pqT[tid * 2048 + blockIdx.x] = lq[tid] + lq[32 + tid] + lq[64 + tid] + lq[96 + tid];
    }
}

// PASS B (f-branch, fp16 in/out): one coalesced full-row load phase into
// padded-LDS halves (stride 66), then pure FMA, then transpose-store + stats.
__launch_bounds__(128, 4)
__global__ void mlp_fB_kernel(const float* __restrict__ W1, const __half* __restrict__ xin,
                              __half* __restrict__ xout) {
    __shared__ float fbuf[64 * 66];       // 16.9 KB; half-view: 128 rows x 66 halves
    __shared__ float ls[128], lq[128];
    __half* hbuf = (__half*)fbuf;
    unsigned int* w32 = (unsigned int*)fbuf;
    int tid = threadIdx.x;
    int rowbase = blockIdx.x * 128;
    {
        const float4* src = (const float4*)xin;
#pragma unroll
        for (int k = 0; k < 8; ++k) {
            int o4 = tid + k * 128;       // 0..1023
            int rloc = o4 >> 3, j = o4 & 7;
            float4 v = src[(size_t)(rowbase + rloc) * 8 + j];
            const unsigned int* s32 = (const unsigned int*)&v;
#pragma unroll
            for (int m = 0; m < 4; ++m) w32[rloc * 33 + 4 * j + m] = s32[m];
        }
    }
    __syncthreads();
    const float* sc0 = g_bnscale[2];
    const float* sh0 = g_bnshift[2];
    float acc2[CF];
#pragma unroll
    for (int ch = 0; ch < CF; ++ch) acc2[ch] = 0.f;
    {
        const __half* hrow = &hbuf[tid * 66];
        for (int c = 0; c < 64; ++c) {
            float h = fmaxf(fmaf(__half2float(hrow[c]), sc0[c], sh0[c]), 0.f);
#pragma unroll
            for (int ch = 0; ch < CF; ++ch)
                acc2[ch] = fmaf(h, W1[c * CF + ch], acc2[ch]);
        }
    }
    float sum = 0.f, sq = 0.f;
#pragma unroll
    for (int p = 0; p < 2; ++p) {
        __syncthreads();
        if ((tid >> 6) == p) {
            float* srow = &fbuf[(tid & 63) * 66];
#pragma unroll
            for (int ch = 0; ch < CF; ++ch) srow[ch] = acc2[ch];
        }
        __syncthreads();
        int ch = tid & 63, rg = tid >> 6;
        for (int r = 0; r < 32; ++r) {
            float v = fbuf[(rg * 32 + r) * 66 + ch];
            xout[(size_t)(rowbase + p * 64 + rg * 32 + r) * CF + ch] = __float2half_rn(v);
            sum += v; sq += v * v;
        }
    }
    ls[tid] = sum; lq[tid] = sq;
    __syncthreads();
    if (tid < 64) {
        g_psT[tid * 2048 + blockIdx.x] = ls[tid] + ls[64 + tid];
        g_pqT[tid * 2048 + blockIdx.x] = lq[tid] + lq[64 + tid];
    }
}

// PASS C deform: stream x1f (fp16), BN1+ReLU, sigmoid weight, max over 32 -> out
__global__ void passC_f_kernel(const float* __restrict__ xyz, const float* __restrict__ newxyz,
                               const float* __restrict__ td, const __half* __restrict__ xin,
                               float* __restrict__ out) {
    __shared__ float lw[64];
    int tid = threadIdx.x;
    int qpair = blockIdx.x * 2;
    if (tid < 64) {
        int ql = tid >> 5, s = tid & 31;
        int q = qpair + ql;
        float wv = 0.f;
        if (!g_empty_d[q]) {
            int idx = g_idx_d[q * SD + s];
            int b = q >> 12;
            float dx = xyz[(size_t)b * NPTS * 3 + idx * 3 + 0] - newxyz[q * 3 + 0];
            float dy = xyz[(size_t)b * NPTS * 3 + idx * 3 + 1] - newxyz[q * 3 + 1];
            float dz = xyz[(size_t)b * NPTS * 3 + idx * 3 + 2] - newxyz[q * 3 + 2];
            float dist = sqrtf(dx * dx + dy * dy + dz * dz);
            float rq = g_rroi[q >> 6];
            wv = 1.f / (1.f + expf(-(rq - dist) / td[0]));
        }
        lw[tid] = wv;
    }
    __syncthreads();
    int ql = tid >> 6, ch = tid & 63;
    int q = qpair + ql;
    float sc = g_bnscale[3][ch], sh = g_bnshift[3][ch];
    float m = 0.f;
    for (int s = 0; s < SD; ++s) {
        float v = __half2float(xin[((size_t)q * SD + s) * CF + ch]);
        m = fmaxf(m, lw[ql * 32 + s] * fmaxf(fmaf(v, sc, sh), 0.f));
    }
    out[MTOT * 3 + (size_t)q * CF + ch] = m;
}

// PASS C pred (fp32): stream x1p, BN1+ReLU, max over 16, dot with fcw -> g_pdot
__global__ void passC_p_kernel(const float* __restrict__ fcw, const float* __restrict__ xin) {
    int tid = threadIdx.x;
    int q = blockIdx.x * 8 + (tid >> 5);
    int ch = tid & 31;
    float sc = g_bnscale[1][ch], sh = g_bnshift[1][ch];
    float m = 0.f;
    for (int s = 0; s < SP; ++s) {
        float v = xin[(size_t)(q * SP + s) * CP + ch] * sc + sh;
        m = fmaxf(m, fmaxf(v, 0.f));
    }
    float pd = m * fcw[(q & 63) * CP + ch];
    for (int off = 16; off > 0; off >>= 1) pd += __shfl_down(pd, off, 32);
    if (ch == 0) g_pdot[q] = pd;
}

// -------- BN stats finalize: one block per channel, coalesced, tree-reduce --
__global__ void finalize_kernel(const float* __restrict__ gamma, const float* __restrict__ beta,
                                float n, int layer, int nblocks) {
    __shared__ double l_s[256], l_q[256];
    int ch = blockIdx.x, tid = threadIdx.x;
    double s = 0, q = 0;
    for (int i = tid; i < nblocks; i += 256) { s += g_psT[ch * 2048 + i]; q += g_pqT[ch * 2048 + i]; }
    l_s[tid] = s; l_q[tid] = q; __syncthreads();
    for (int off = 128; off > 0; off >>= 1) {
        if (tid < off) { l_s[tid] += l_s[tid + off]; l_q[tid] += l_q[tid + off]; }
        __syncthreads();
    }
    if (tid == 0) {
        double mu = l_s[0] / (double)n;
        double var = l_q[0] / (double)n - mu * mu;
        if (var < 0) var = 0;
        double sc = (double)gamma[ch] / sqrt(var + 1e-5);
        g_bnscale[layer][ch] = (float)sc;
        g_bnshift[layer][ch] = (float)((double)beta[ch] - mu * sc);
    }
}

// ---------------- per-roi fc reduce -> deform radius -----------------------
__global__ void roi_r_kernel(const float* __restrict__ roif, const float* __restrict__ fcw,
                             const float* __restrict__ fcb) {
    int tid = threadIdx.x;
    int roi = blockIdx.x * 4 + (tid >> 6);
    int lane = tid & 63;
    float acc = g_pdot[roi * 64 + lane]
              + roif[roi * 128 + lane]      * fcw[2048 + lane]
              + roif[roi * 128 + 64 + lane] * fcw[2048 + 64 + lane];
    for (int off = 32; off > 0; off >>= 1) acc += __shfl_down(acc, off, 64);
    if (lane == 0) {
        float res = acc + fcb[0];
        g_rroi[roi] = fmaxf(res / DIV_COEF_C + RADIUS_C, MIN_R_C);
    }
}

extern "C" void kernel_launch(void* const* d_in, const int* in_sizes, int n_in,
                              void* d_out, int out_size, void* d_ws, size_t ws_size,
                              hipStream_t stream) {
    const float* xyz   = (const float*)d_in[0];
    const float* feats = (const float*)d_in[1];
    const float* rois  = (const float*)d_in[2];
    const float* roif  = (const float*)d_in[3];
    const float* td    = (const float*)d_in[4];
    const float* pw0 = (const float*)d_in[5];
    const float* pg0 = (const float*)d_in[6];
    const float* pb0 = (const float*)d_in[7];
    const float* pw1 = (const float*)d_in[8];
    const float* pg1 = (const float*)d_in[9];
    const float* pb1 = (const float*)d_in[10];
    const float* fw0 = (const float*)d_in[11];
    const float* fg0 = (const float*)d_in[12];
    const float* fb0 = (const float*)d_in[13];
    const float* fw1 = (const float*)d_in[14];
    const float* fg1 = (const float*)d_in[15];
    const float* fb1 = (const float*)d_in[16];
    const float* fcw = (const float*)d_in[17];
    const float* fcb = (const float*)d_in[18];
    float* out = (float*)d_out;

    void* xa; hipGetSymbolAddress(&xa, HIP_SYMBOL(g_xa));
    void* xb; hipGetSymbolAddress(&xb, HIP_SYMBOL(g_xb));

    copy_xyz_kernel<<<96, 256, 0, stream>>>(rois, out);

    // grid build (once; reused by both ball queries)
    grid_zero_kernel<<<2, 1024, 0, stream>>>();
    grid_count_kernel<<<64, 256, 0, stream>>>(xyz);
    grid_prefix_kernel<<<1, 1024, 0, stream>>>();
    grid_scatter_kernel<<<64, 256, 0, stream>>>();
    grid_sort_kernel<<<7, 256, 0, stream>>>();

    // pred branch (16 samples, 32 ch, all fp32 -> radii bit-identical)
    bq_grid_kernel<SP><<<MTOT / 4, 256, 0, stream>>>(xyz, rois);
    mlp_passA_kernel<SP, CP, false><<<1024, 128, 0, stream>>>(xyz, feats, rois, pw0, xa);
    finalize_kernel<<<CP, 256, 0, stream>>>(pg0, pb0, (float)(MTOT * SP), 0, 1024);
    mlp_passB_kernel<SP, CP><<<1024, 128, 0, stream>>>(pw1, (const float*)xa, (float*)xb, 0);
    finalize_kernel<<<CP, 256, 0, stream>>>(pg1, pb1, (float)(MTOT * SP), 1, 1024);
    passC_p_kernel<<<MTOT / 8, 256, 0, stream>>>(fcw, (const float*)xb);
    roi_r_kernel<<<NROI / 4, 256, 0, stream>>>(roif, fcw, fcb);

    // deform branch (32 samples, 64 ch, fp16 intermediates)
    bq_grid_kernel<SD><<<MTOT / 4, 256, 0, stream>>>(xyz, rois);
    mlp_passA_kernel<SD, CF, true><<<2048, 128, 0, stream>>>(xyz, feats, rois, fw0, xa);
    finalize_kernel<<<CF, 256, 0, stream>>>(fg0, fb0, (float)(MTOT * SD), 2, 2048);
    mlp_fB_kernel<<<2048, 128, 0, stream>>>(fw1, (const __half*)xa, (__half*)xb);
    finalize_kernel<<<CF, 256, 0, stream>>>(fg1, fb1, (float)(MTOT * SD), 3, 2048);
    passC_f_kernel<<<MTOT / 2, 128, 0, stream>>>(xyz, rois, td, (const __half*)xb, out);
}

// Round 5
// 268.518 us; speedup vs baseline: 1.2098x; 1.2098x over previous
//
#include <hip/hip_runtime.h>
#include <hip/hip_fp16.h>

#define NB 2
#define NPTS 8192
#define NQ 4096
#define MTOT 8192      // NB*NQ
#define SP 16
#define SD 32
#define CIN 32
#define CP 32
#define CF 64
#define NROI 128       // NB*64
#define RADIUS_C 0.8f
#define MIN_R_C 0.01f
#define DIV_COEF_C 10.0f

// ---- spatial grid (cell = radius = 0.8; scene = [10,10,4]) ----------------
#define INV_CS 1.25f
#define NCX 13
#define NCY 13
#define NCZ 5
#define NCELL (NCX * NCY * NCZ)   // 845

// ---------------- device-global scratch (fully rewritten every call) -------
__device__ int    g_idx_p[MTOT * SP];
__device__ int    g_empty_p[MTOT];
__device__ int    g_idx_d[MTOT * SD];
__device__ int    g_empty_d[MTOT];
__device__ int    g_cellcnt[NB][NCELL];
__device__ int    g_cellcur[NB][NCELL];
__device__ int    g_cellstart[NB][NCELL + 1];
__device__ float4 g_cellxyzw[NB][NPTS];   // packed (x,y,z,index) per reordered point
// generic activation buffers: p-branch uses fp32 (16.7MB), f-branch fp16 (33.5MB)
__device__ unsigned char g_xa[(size_t)MTOT * SD * CF * 2];
__device__ unsigned char g_xb[(size_t)MTOT * SD * CF * 2];
__device__ float g_psT[CF * 2048];                // transposed: [ch][block]
__device__ float g_pqT[CF * 2048];
__device__ float g_bnscale[4][CF];                // 0=p0 1=p1 2=f0 3=f1
__device__ float g_bnshift[4][CF];
__device__ float g_pdot[MTOT];
__device__ float g_rroi[NROI];

// ---------------- new_xyz output is rois flattened -------------------------
__global__ void copy_xyz_kernel(const float* __restrict__ rois, float* __restrict__ out) {
    int i = blockIdx.x * 256 + threadIdx.x;
    if (i < MTOT * 3) out[i] = rois[i];
}

// ================= grid build (shared by both bq calls) =====================
__global__ void grid_zero_kernel() {
    int i = blockIdx.x * 1024 + threadIdx.x;
    if (i < NB * NCELL) ((int*)g_cellcnt)[i] = 0;
}

__device__ __forceinline__ int cell_of(float x, float y, float z) {
    int cx = min(NCX - 1, max(0, (int)floorf(x * INV_CS)));
    int cy = min(NCY - 1, max(0, (int)floorf(y * INV_CS)));
    int cz = min(NCZ - 1, max(0, (int)floorf(z * INV_CS)));
    return (cz * NCY + cy) * NCX + cx;
}

__global__ void grid_count_kernel(const float* __restrict__ xyz) {
    int i = blockIdx.x * 256 + threadIdx.x;   // 0..16383
    int b = i >> 13;
    int cell = cell_of(xyz[(size_t)i * 3 + 0], xyz[(size_t)i * 3 + 1], xyz[(size_t)i * 3 + 2]);
    atomicAdd(&g_cellcnt[b][cell], 1);
}

__global__ void grid_prefix_kernel() {     // one block per batch
    __shared__ int sc[1024];
    int b = blockIdx.x, tid = threadIdx.x;
    int v = (tid < NCELL) ? g_cellcnt[b][tid] : 0;
    sc[tid] = v;
    __syncthreads();
    for (int off = 1; off < 1024; off <<= 1) {
        int add = (tid >= off) ? sc[tid - off] : 0;
        __syncthreads();
        sc[tid] += add;
        __syncthreads();
    }
    if (tid < NCELL) {
        int excl = sc[tid] - v;
        g_cellstart[b][tid] = excl;
        g_cellcur[b][tid] = excl;
    }
    if (tid == 0) g_cellstart[b][NCELL] = NPTS;
}

__global__ void grid_scatter_kernel(const float* __restrict__ xyz) {
    int i = blockIdx.x * 256 + threadIdx.x;
    int b = i >> 13, il = i & (NPTS - 1);
    float x = xyz[(size_t)i * 3 + 0];
    float y = xyz[(size_t)i * 3 + 1];
    float z = xyz[(size_t)i * 3 + 2];
    int cell = cell_of(x, y, z);
    int pos = atomicAdd(&g_cellcur[b][cell], 1);
    g_cellxyzw[b][pos] = make_float4(x, y, z, __int_as_float(il));
}

// ======= ball query via grid: one wave/query, register candidates, =========
// ======= threshold-selection of NS smallest (order is irrelevant    =========
// ======= downstream: BN sums / max-pools are order-invariant)       =========
template <int NS>
__launch_bounds__(256, 8)
__global__ void bq_grid_kernel(const float* __restrict__ xyz, const float* __restrict__ newxyz) {
    __shared__ int s_epos[4][512];
    int tid = threadIdx.x, wv = tid >> 6, lane = tid & 63;
    int q = blockIdx.x * 4 + wv;
    int b = q >> 12;
    float qx = newxyz[q * 3 + 0], qy = newxyz[q * 3 + 1], qz = newxyz[q * 3 + 2];
    float r = (NS == SP) ? RADIUS_C : g_rroi[q >> 6];
    float r2 = r * r;
    int* idx_out   = (NS == SP) ? g_idx_p   : g_idx_d;
    int* empty_out = (NS == SP) ? g_empty_p : g_empty_d;

    float rp = r + 1e-4f;                 // cell-range padding (fp safety)
    int xlo = max(0, min(NCX - 1, (int)floorf((qx - rp) * INV_CS)));
    int xhi = max(0, min(NCX - 1, (int)floorf((qx + rp) * INV_CS)));
    int ylo = max(0, min(NCY - 1, (int)floorf((qy - rp) * INV_CS)));
    int yhi = max(0, min(NCY - 1, (int)floorf((qy + rp) * INV_CS)));
    int zlo = max(0, min(NCZ - 1, (int)floorf((qz - rp) * INV_CS)));
    int zhi = max(0, min(NCZ - 1, (int)floorf((qz + rp) * INV_CS)));
    int nx = xhi - xlo + 1, ny = yhi - ylo + 1, nz = zhi - zlo + 1;
    int ncell = nx * ny * nz;

    // phase A: lane = candidate cell; sizes + wave prefix
    int cstart = 0, ccnt = 0;
    if (lane < ncell) {
        int cx = xlo + (lane % nx);
        int t1 = lane / nx;
        int cy = ylo + (t1 % ny);
        int cz = zlo + (t1 / ny);
        int cell = (cz * NCY + cy) * NCX + cx;
        cstart = g_cellstart[b][cell];
        ccnt = g_cellstart[b][cell + 1] - cstart;
    }
    int incl = ccnt;
#pragma unroll
    for (int off = 1; off < 64; off <<= 1) {
        int n = __shfl_up(incl, off, 64);
        if (lane >= off) incl += n;
    }
    int T = __shfl(incl, 63, 64);
    int pre = incl - ccnt;

    if (ncell > 64 || T > 512) {
        // rare fallback: ordered full scan (exact original semantics)
        const float* xb = xyz + (size_t)b * NPTS * 3;
        int cnt2 = 0, first_idx = 0;
        for (int g = 0; g < NPTS / 64 && cnt2 < NS; ++g) {
            int p = (g << 6) + lane;
            float dx = qx - xb[3 * p + 0];
            float dy = qy - xb[3 * p + 1];
            float dz = qz - xb[3 * p + 2];
            bool valid = (dx * dx + dy * dy + dz * dz) < r2;
            unsigned long long mask = __ballot(valid);
            if (cnt2 == 0 && mask) first_idx = (g << 6) + (int)__builtin_ctzll(mask);
            int pos = cnt2 + __popcll(mask & ((1ull << lane) - 1ull));
            if (valid && pos < NS) idx_out[q * NS + pos] = p;
            cnt2 += (int)__popcll(mask);
        }
        if (cnt2 == 0) {
            if (lane < NS) idx_out[q * NS + lane] = 0;
            if (lane == 0) empty_out[q] = 1;
        } else {
            int filled = cnt2 < NS ? cnt2 : NS;
            if (lane >= filled && lane < NS) idx_out[q * NS + lane] = first_idx;
            if (lane == 0) empty_out[q] = 0;
        }
        return;
    }

    // scatter entry positions (independent LDS writes, lanes parallel)
    for (int k = 0; k < ccnt; ++k) s_epos[wv][pre + k] = cstart + k;
    __asm__ volatile("s_waitcnt lgkmcnt(0)" ::: "memory");

    // phase B: lane = candidate slot; 8 register slots; 1 packed load each
    int p[8];
#pragma unroll
    for (int k = 0; k < 8; ++k) {
        int t = k * 64 + lane;
        int pk = 0x7FFFFFFF;
        if (t < T) {
            int e = s_epos[wv][t];
            float4 v = g_cellxyzw[b][e];
            float dx = qx - v.x, dy = qy - v.y, dz = qz - v.z;
            if (dx * dx + dy * dy + dz * dz < r2) pk = __float_as_int(v.w);
        }
        p[k] = pk;
    }

    // phase C: wave stats
    int lcnt = 0, lmin = 0x7FFFFFFF;
#pragma unroll
    for (int k = 0; k < 8; ++k) {
        if (p[k] != 0x7FFFFFFF) { ++lcnt; lmin = min(lmin, p[k]); }
    }
    int cnt = lcnt, fidx = lmin;
#pragma unroll
    for (int off = 1; off < 64; off <<= 1) {
        cnt += __shfl_xor(cnt, off, 64);
        fidx = min(fidx, __shfl_xor(fidx, off, 64));
    }
    if (cnt == 0) {
        if (lane < NS) idx_out[q * NS + lane] = 0;
        if (lane == 0) empty_out[q] = 1;
        return;
    }
    // threshold = smallest m with #(p < m) >= NS  (indices distinct -> exact NS)
    int thr = 0x7FFFFFFF;
    if (cnt > NS) {
        int lo = 0, hi = NPTS;
        while (lo < hi) {
            int mid = (lo + hi) >> 1;
            int c = 0;
#pragma unroll
            for (int k = 0; k < 8; ++k) c += (p[k] < mid) ? 1 : 0;
#pragma unroll
            for (int off = 1; off < 64; off <<= 1) c += __shfl_xor(c, off, 64);
            if (c >= NS) hi = mid; else lo = mid + 1;
        }
        thr = lo;
    }
    // write qualifying slots at wave-prefix positions (order irrelevant)
    int qc = 0;
#pragma unroll
    for (int k = 0; k < 8; ++k) qc += (p[k] < thr) ? 1 : 0;
    int qincl = qc;
#pragma unroll
    for (int off = 1; off < 64; off <<= 1) {
        int n = __shfl_up(qincl, off, 64);
        if (lane >= off) qincl += n;
    }
    int pos = qincl - qc;
#pragma unroll
    for (int k = 0; k < 8; ++k) {
        if (p[k] < thr) {
            if (pos < NS) idx_out[q * NS + pos] = p[k];
            ++pos;
        }
    }
    if (lane >= cnt && lane < NS) idx_out[q * NS + lane] = fidx;   // pads
    if (lane == 0) empty_out[q] = 0;
}

// ============ 3-pass MLP =====================================================
// PASS A: gather -> L0 -> store x0 (fp32 for p-branch, fp16 for f-branch) + stats
// block = 128 threads (2 waves), LDS <= 19.5 KB.
template <int NS, int CH, bool HALF>
__launch_bounds__(128, 4)
__global__ void mlp_passA_kernel(const float* __restrict__ xyz, const float* __restrict__ feats,
                                 const float* __restrict__ newxyz, const float* __restrict__ W0,
                                 void* __restrict__ xout_) {
    constexpr int GSTR = 37;        // gather row stride (35 used)
    constexpr int SST  = CH + 2;    // stats/store transpose stride
    __shared__ float buf[128 * GSTR];
    __shared__ float ls[128], lq[128];
    int tid = threadIdx.x;
    int rowbase = blockIdx.x * 128;
    int row = rowbase + tid;
    int q = row / NS, b = q >> 12;
    const int* idx_arr = (NS == SP) ? g_idx_p : g_idx_d;
    const int* emp_arr = (NS == SP) ? g_empty_p : g_empty_d;
    {
        float* dst = &buf[tid * GSTR];
        if (emp_arr[q]) {
#pragma unroll
            for (int c = 0; c < 35; ++c) dst[c] = 0.f;
        } else {
            int idx = idx_arr[row];
            const float* xp = xyz + (size_t)b * NPTS * 3 + idx * 3;
            dst[0] = xp[0] - newxyz[q * 3 + 0];
            dst[1] = xp[1] - newxyz[q * 3 + 1];
            dst[2] = xp[2] - newxyz[q * 3 + 2];
            const float4* fp = (const float4*)(feats + (size_t)b * NPTS * CIN + (size_t)idx * CIN);
#pragma unroll
            for (int j = 0; j < 8; ++j) {
                float4 v = fp[j];
                dst[3 + 4 * j + 0] = v.x; dst[3 + 4 * j + 1] = v.y;
                dst[3 + 4 * j + 2] = v.z; dst[3 + 4 * j + 3] = v.w;
            }
        }
    }
    // L0 from own LDS row (no barrier needed)
    float acc[CH];
#pragma unroll
    for (int ch = 0; ch < CH; ++ch) acc[ch] = 0.f;
    {
        const float* inrow = &buf[tid * GSTR];
        for (int c = 0; c < 35; ++c) {
            float h = inrow[c];
#pragma unroll
            for (int ch = 0; ch < CH; ++ch) acc[ch] = fmaf(h, W0[c * CH + ch], acc[ch]);
        }
    }
    // stats (fp32, pre-rounding) + coalesced store via chunked LDS transpose
    float* xf = (float*)xout_;
    __half* xh = (__half*)xout_;
    float sum = 0.f, sq = 0.f;
#pragma unroll
    for (int p = 0; p < 2; ++p) {
        __syncthreads();
        if ((tid >> 6) == p) {
            float* srow = &buf[(tid & 63) * SST];
#pragma unroll
            for (int ch = 0; ch < CH; ++ch) srow[ch] = acc[ch];
        }
        __syncthreads();
        if (CH == 64) {
            int ch = tid & 63, rg = tid >> 6;
            for (int r = 0; r < 32; ++r) {
                float v = buf[(rg * 32 + r) * SST + ch];
                size_t o = (size_t)(rowbase + p * 64 + rg * 32 + r) * CH + ch;
                if (HALF) xh[o] = __float2half_rn(v); else xf[o] = v;
                sum += v; sq += v * v;
            }
        } else {
            int ch = tid & 31, rg = tid >> 5;
            for (int r = 0; r < 16; ++r) {
                float v = buf[(rg * 16 + r) * SST + ch];
                size_t o = (size_t)(rowbase + p * 64 + rg * 16 + r) * CH + ch;
                if (HALF) xh[o] = __float2half_rn(v); else xf[o] = v;
                sum += v; sq += v * v;
            }
        }
    }
    ls[tid] = sum; lq[tid] = sq;
    __syncthreads();
    if (CH == 64) {
        if (tid < 64) {
            g_psT[tid * 2048 + blockIdx.x] = ls[tid] + ls[64 + tid];
            g_pqT[tid * 2048 + blockIdx.x] = lq[tid] + lq[64 + tid];
        }
    } else {
        if (tid < 32) {
            g_psT[tid * 2048 + blockIdx.x] = ls[tid] + ls[32 + tid] + ls[64 + tid] + ls[96 + tid];
            g_pqT[tid * 2048 + blockIdx.x] = lq[tid] + lq[32 + tid] + lq[64 + tid] + lq[96 + tid];
        }
    }
}

// PASS B (p-branch, fp32): stream x0p -> BN0+ReLU -> L1 -> store x1p + stats
template <int NS, int CH>
__launch_bounds__(128, 4)
__global__ void mlp_passB_kernel(const float* __restrict__ W1, const float* __restrict__ xin,
                                 float* __restrict__ xout, int bn0) {
    constexpr int HSTR = 33;
    constexpr int SST  = CH + 2;
    __shared__ float buf[128 * 37];
    __shared__ float ls[128], lq[128];
    int tid = threadIdx.x;
    int rowbase = blockIdx.x * 128;
    const float* sc0 = g_bnscale[bn0];
    const float* sh0 = g_bnshift[bn0];
    float acc2[CH];
#pragma unroll
    for (int ch = 0; ch < CH; ++ch) acc2[ch] = 0.f;
    const float4* src = (const float4*)xin;
#pragma unroll
    for (int hc = 0; hc < CH / 32; ++hc) {
        if (hc) __syncthreads();
#pragma unroll
        for (int k = 0; k < 8; ++k) {
            int o4 = tid + k * 128;       // 0..1023
            int rloc = o4 >> 3, j = o4 & 7;
            int c = 4 * j, gc = hc * 32 + c;
            float4 v = src[(size_t)(rowbase + rloc) * (CH / 4) + hc * 8 + j];
            float* d = &buf[rloc * HSTR + c];
            d[0] = fmaxf(fmaf(v.x, sc0[gc + 0], sh0[gc + 0]), 0.f);
            d[1] = fmaxf(fmaf(v.y, sc0[gc + 1], sh0[gc + 1]), 0.f);
            d[2] = fmaxf(fmaf(v.z, sc0[gc + 2], sh0[gc + 2]), 0.f);
            d[3] = fmaxf(fmaf(v.w, sc0[gc + 3], sh0[gc + 3]), 0.f);
        }
        __syncthreads();
        const float* hrow = &buf[tid * HSTR];
        for (int c = 0; c < 32; ++c) {
            float h = hrow[c];
#pragma unroll
            for (int ch = 0; ch < CH; ++ch)
                acc2[ch] = fmaf(h, W1[(hc * 32 + c) * CH + ch], acc2[ch]);
        }
    }
    float sum = 0.f, sq = 0.f;
#pragma unroll
    for (int p = 0; p < 2; ++p) {
        __syncthreads();
        if ((tid >> 6) == p) {
            float* srow = &buf[(tid & 63) * SST];
#pragma unroll
            for (int ch = 0; ch < CH; ++ch) srow[ch] = acc2[ch];
        }
        __syncthreads();
        int ch = tid & 31, rg = tid >> 5;
        for (int r = 0; r < 16; ++r) {
            float v = buf[(rg * 16 + r) * SST + ch];
            xout[(size_t)(rowbase + p * 64 + rg * 16 + r) * CH + ch] = v;
            sum += v; sq += v * v;
        }
    }
    ls[tid] = sum; lq[tid] = sq;
    __syncthreads();
    if (tid < 32) {
        g_psT[tid * 2048 + blockIdx.x] = ls[tid] + ls[32 + tid] + ls[64 + tid] + ls[96 + tid];
        g_pqT[tid * 2048 + blockIdx.x] = lq[tid] + lq[32 + tid] + lq[64 + tid] + lq[96 + tid];
    }
}

// PASS B (f-branch, fp16 in/out): one coalesced full-row load phase into
// padded-LDS halves (stride 66), then pure FMA, then transpose-store + stats.
__launch_bounds__(128, 4)
__global__ void mlp_fB_kernel(const float* __restrict__ W1, const __half* __restrict__ xin,
                              __half* __restrict__ xout) {
    __shared__ float fbuf[64 * 66];       // 16.9 KB; half-view: 128 rows x 66 halves
    __shared__ float ls[128], lq[128];
    __half* hbuf = (__half*)fbuf;
    unsigned int* w32 = (unsigned int*)fbuf;
    int tid = threadIdx.x;
    int rowbase = blockIdx.x * 128;
    {
        const float4* src = (const float4*)xin;
#pragma unroll
        for (int k = 0; k < 8; ++k) {
            int o4 = tid + k * 128;       // 0..1023
            int rloc = o4 >> 3, j = o4 & 7;
            float4 v = src[(size_t)(rowbase + rloc) * 8 + j];
            const unsigned int* s32 = (const unsigned int*)&v;
#pragma unroll
            for (int m = 0; m < 4; ++m) w32[rloc * 33 + 4 * j + m] = s32[m];
        }
    }
    __syncthreads();
    const float* sc0 = g_bnscale[2];
    const float* sh0 = g_bnshift[2];
    float acc2[CF];
#pragma unroll
    for (int ch = 0; ch < CF; ++ch) acc2[ch] = 0.f;
    {
        const __half* hrow = &hbuf[tid * 66];
        for (int c = 0; c < 64; ++c) {
            float h = fmaxf(fmaf(__half2float(hrow[c]), sc0[c], sh0[c]), 0.f);
#pragma unroll
            for (int ch = 0; ch < CF; ++ch)
                acc2[ch] = fmaf(h, W1[c * CF + ch], acc2[ch]);
        }
    }
    float sum = 0.f, sq = 0.f;
#pragma unroll
    for (int p = 0; p < 2; ++p) {
        __syncthreads();
        if ((tid >> 6) == p) {
            float* srow = &fbuf[(tid & 63) * 66];
#pragma unroll
            for (int ch = 0; ch < CF; ++ch) srow[ch] = acc2[ch];
        }
        __syncthreads();
        int ch = tid & 63, rg = tid >> 6;
        for (int r = 0; r < 32; ++r) {
            float v = fbuf[(rg * 32 + r) * 66 + ch];
            xout[(size_t)(rowbase + p * 64 + rg * 32 + r) * CF + ch] = __float2half_rn(v);
            sum += v; sq += v * v;
        }
    }
    ls[tid] = sum; lq[tid] = sq;
    __syncthreads();
    if (tid < 64) {
        g_psT[tid * 2048 + blockIdx.x] = ls[tid] + ls[64 + tid];
        g_pqT[tid * 2048 + blockIdx.x] = lq[tid] + lq[64 + tid];
    }
}

// PASS C deform: stream x1f (fp16), BN1+ReLU, sigmoid weight, max over 32 -> out
__global__ void passC_f_kernel(const float* __restrict__ xyz, const float* __restrict__ newxyz,
                               const float* __restrict__ td, const __half* __restrict__ xin,
                               float* __restrict__ out) {
    __shared__ float lw[64];
    int tid = threadIdx.x;
    int qpair = blockIdx.x * 2;
    if (tid < 64) {
        int ql = tid >> 5, s = tid & 31;
        int q = qpair + ql;
        float wv = 0.f;
        if (!g_empty_d[q]) {
            int idx = g_idx_d[q * SD + s];
            int b = q >> 12;
            float dx = xyz[(size_t)b * NPTS * 3 + idx * 3 + 0] - newxyz[q * 3 + 0];
            float dy = xyz[(size_t)b * NPTS * 3 + idx * 3 + 1] - newxyz[q * 3 + 1];
            float dz = xyz[(size_t)b * NPTS * 3 + idx * 3 + 2] - newxyz[q * 3 + 2];
            float dist = sqrtf(dx * dx + dy * dy + dz * dz);
            float rq = g_rroi[q >> 6];
            wv = 1.f / (1.f + expf(-(rq - dist) / td[0]));
        }
        lw[tid] = wv;
    }
    __syncthreads();
    int ql = tid >> 6, ch = tid & 63;
    int q = qpair + ql;
    float sc = g_bnscale[3][ch], sh = g_bnshift[3][ch];
    float m = 0.f;
    for (int s = 0; s < SD; ++s) {
        float v = __half2float(xin[((size_t)q * SD + s) * CF + ch]);
        m = fmaxf(m, lw[ql * 32 + s] * fmaxf(fmaf(v, sc, sh), 0.f));
    }
    out[MTOT * 3 + (size_t)q * CF + ch] = m;
}

// PASS C pred (fp32): stream x1p, BN1+ReLU, max over 16, dot with fcw -> g_pdot
__global__ void passC_p_kernel(const float* __restrict__ fcw, const float* __restrict__ xin) {
    int tid = threadIdx.x;
    int q = blockIdx.x * 8 + (tid >> 5);
    int ch = tid & 31;
    float sc = g_bnscale[1][ch], sh = g_bnshift[1][ch];
    float m = 0.f;
    for (int s = 0; s < SP; ++s) {
        float v = xin[(size_t)(q * SP + s) * CP + ch] * sc + sh;
        m = fmaxf(m, fmaxf(v, 0.f));
    }
    float pd = m * fcw[(q & 63) * CP + ch];
    for (int off = 16; off > 0; off >>= 1) pd += __shfl_down(pd, off, 32);
    if (ch == 0) g_pdot[q] = pd;
}

// -------- BN stats finalize: one block per channel, coalesced, tree-reduce --
__global__ void finalize_kernel(const float* __restrict__ gamma, const float* __restrict__ beta,
                                float n, int layer, int nblocks) {
    __shared__ double l_s[256], l_q[256];
    int ch = blockIdx.x, tid = threadIdx.x;
    double s = 0, q = 0;
    for (int i = tid; i < nblocks; i += 256) { s += g_psT[ch * 2048 + i]; q += g_pqT[ch * 2048 + i]; }
    l_s[tid] = s; l_q[tid] = q; __syncthreads();
    for (int off = 128; off > 0; off >>= 1) {
        if (tid < off) { l_s[tid] += l_s[tid + off]; l_q[tid] += l_q[tid + off]; }
        __syncthreads();
    }
    if (tid == 0) {
        double mu = l_s[0] / (double)n;
        double var = l_q[0] / (double)n - mu * mu;
        if (var < 0) var = 0;
        double sc = (double)gamma[ch] / sqrt(var + 1e-5);
        g_bnscale[layer][ch] = (float)sc;
        g_bnshift[layer][ch] = (float)((double)beta[ch] - mu * sc);
    }
}

// ---------------- per-roi fc reduce -> deform radius -----------------------
__global__ void roi_r_kernel(const float* __restrict__ roif, const float* __restrict__ fcw,
                             const float* __restrict__ fcb) {
    int tid = threadIdx.x;
    int roi = blockIdx.x * 4 + (tid >> 6);
    int lane = tid & 63;
    float acc = g_pdot[roi * 64 + lane]
              + roif[roi * 128 + lane]      * fcw[2048 + lane]
              + roif[roi * 128 + 64 + lane] * fcw[2048 + 64 + lane];
    for (int off = 32; off > 0; off >>= 1) acc += __shfl_down(acc, off, 64);
    if (lane == 0) {
        float res = acc + fcb[0];
        g_rroi[roi] = fmaxf(res / DIV_COEF_C + RADIUS_C, MIN_R_C);
    }
}

extern "C" void kernel_launch(void* const* d_in, const int* in_sizes, int n_in,
                              void* d_out, int out_size, void* d_ws, size_t ws_size,
                              hipStream_t stream) {
    const float* xyz   = (const float*)d_in[0];
    const float* feats = (const float*)d_in[1];
    const float* rois  = (const float*)d_in[2];
    const float* roif  = (const float*)d_in[3];
    const float* td    = (const float*)d_in[4];
    const float* pw0 = (const float*)d_in[5];
    const float* pg0 = (const float*)d_in[6];
    const float* pb0 = (const float*)d_in[7];
    const float* pw1 = (const float*)d_in[8];
    const float* pg1 = (const float*)d_in[9];
    const float* pb1 = (const float*)d_in[10];
    const float* fw0 = (const float*)d_in[11];
    const float* fg0 = (const float*)d_in[12];
    const float* fb0 = (const float*)d_in[13];
    const float* fw1 = (const float*)d_in[14];
    const float* fg1 = (const float*)d_in[15];
    const float* fb1 = (const float*)d_in[16];
    const float* fcw = (const float*)d_in[17];
    const float* fcb = (const float*)d_in[18];
    float* out = (float*)d_out;

    void* xa; hipGetSymbolAddress(&xa, HIP_SYMBOL(g_xa));
    void* xb; hipGetSymbolAddress(&xb, HIP_SYMBOL(g_xb));

    copy_xyz_kernel<<<96, 256, 0, stream>>>(rois, out);

    // grid build (once; reused by both ball queries; no per-cell sort needed)
    grid_zero_kernel<<<2, 1024, 0, stream>>>();
    grid_count_kernel<<<64, 256, 0, stream>>>(xyz);
    grid_prefix_kernel<<<2, 1024, 0, stream>>>();
    grid_scatter_kernel<<<64, 256, 0, stream>>>(xyz);

    // pred branch (16 samples, 32 ch, all fp32)
    bq_grid_kernel<SP><<<MTOT / 4, 256, 0, stream>>>(xyz, rois);
    mlp_passA_kernel<SP, CP, false><<<1024, 128, 0, stream>>>(xyz, feats, rois, pw0, xa);
    finalize_kernel<<<CP, 256, 0, stream>>>(pg0, pb0, (float)(MTOT * SP), 0, 1024);
    mlp_passB_kernel<SP, CP><<<1024, 128, 0, stream>>>(pw1, (const float*)xa, (float*)xb, 0);
    finalize_kernel<<<CP, 256, 0, stream>>>(pg1, pb1, (float)(MTOT * SP), 1, 1024);
    passC_p_kernel<<<MTOT / 8, 256, 0, stream>>>(fcw, (const float*)xb);
    roi_r_kernel<<<NROI / 4, 256, 0, stream>>>(roif, fcw, fcb);

    // deform branch (32 samples, 64 ch, fp16 intermediates)
    bq_grid_kernel<SD><<<MTOT / 4, 256, 0, stream>>>(xyz, rois);
    mlp_passA_kernel<SD, CF, true><<<2048, 128, 0, stream>>>(xyz, feats, rois, fw0, xa);
    finalize_kernel<<<CF, 256, 0, stream>>>(fg0, fb0, (float)(MTOT * SD), 2, 2048);
    mlp_fB_kernel<<<2048, 128, 0, stream>>>(fw1, (const __half*)xa, (__half*)xb);
    finalize_kernel<<<CF, 256, 0, stream>>>(fg1, fb1, (float)(MTOT * SD), 3, 2048);
    passC_f_kernel<<<MTOT / 2, 128, 0, stream>>>(xyz, rois, td, (const __half*)xb, out);
}

// Round 6
// 267.921 us; speedup vs baseline: 1.2125x; 1.0022x over previous
//
#include <hip/hip_runtime.h>
#include <hip/hip_fp16.h>

#define NB 2
#define NPTS 8192
#define NQ 4096
#define MTOT 8192      // NB*NQ
#define SP 16
#define SD 32
#define CIN 32
#define CP 32
#define CF 64
#define NROI 128       // NB*64
#define RADIUS_C 0.8f
#define MIN_R_C 0.01f
#define DIV_COEF_C 10.0f

// ---- spatial grid (cell = radius = 0.8; scene = [10,10,4]) ----------------
#define INV_CS 1.25f
#define NCX 13
#define NCY 13
#define NCZ 5
#define NCELL (NCX * NCY * NCZ)   // 845

// ---------------- device-global scratch (fully rewritten every call) -------
__device__ int    g_idx_p[MTOT * SP];
__device__ int    g_empty_p[MTOT];
__device__ int    g_idx_d[MTOT * SD];
__device__ int    g_empty_d[MTOT];
__device__ int    g_cellcnt[NB][NCELL];
__device__ int    g_cellcur[NB][NCELL];
__device__ int    g_cellstart[NB][NCELL + 1];
__device__ float4 g_cellxyzw[NB][NPTS];   // packed (x,y,z,index) per reordered point
// generic activation buffers: p-branch uses fp32 (16.7MB), f-branch fp16 (33.5MB)
__device__ unsigned char g_xa[(size_t)MTOT * SD * CF * 2];
__device__ unsigned char g_xb[(size_t)MTOT * SD * CF * 2];
__device__ unsigned int g_w1h[CF * CF / 2];       // W1 as half2 pairs: [ch][c2]
__device__ float g_psT[CF * 2048];                // transposed: [ch][block]
__device__ float g_pqT[CF * 2048];
__device__ float g_bnscale[4][CF];                // 0=p0 1=p1 2=f0 3=f1
__device__ float g_bnshift[4][CF];
__device__ float g_pdot[MTOT];
__device__ float g_rroi[NROI];

typedef _Float16 h2v __attribute__((ext_vector_type(2)));
__device__ __forceinline__ float fdot2f(unsigned int a, unsigned int b, float c) {
#if defined(__has_builtin)
#if __has_builtin(__builtin_amdgcn_fdot2)
    h2v ha, hb;
    ha = *(h2v*)&a; hb = *(h2v*)&b;
    return __builtin_amdgcn_fdot2(ha, hb, c, false);
#else
    __half2 ha = *(__half2*)&a, hb = *(__half2*)&b;
    float2 fa = __half22float2(ha), fb = __half22float2(hb);
    return fmaf(fa.x, fb.x, fmaf(fa.y, fb.y, c));
#endif
#else
    __half2 ha = *(__half2*)&a, hb = *(__half2*)&b;
    float2 fa = __half22float2(ha), fb = __half22float2(hb);
    return fmaf(fa.x, fb.x, fmaf(fa.y, fb.y, c));
#endif
}

// ---------------- new_xyz output is rois flattened -------------------------
__global__ void copy_xyz_kernel(const float* __restrict__ rois, float* __restrict__ out) {
    int i = blockIdx.x * 256 + threadIdx.x;
    if (i < MTOT * 3) out[i] = rois[i];
}

// -------- pack W1 (64x64 fp32) into half2 pairs along c: g_w1h[ch*32+c2] ---
__global__ void prep_w1_kernel(const float* __restrict__ fw1) {
    int i = blockIdx.x * 256 + threadIdx.x;   // 0..2047
    if (i >= CF * CF / 2) return;
    int ch = i >> 5, c2 = i & 31;
    __half2 h = __floats2half2_rn(fw1[(2 * c2) * CF + ch], fw1[(2 * c2 + 1) * CF + ch]);
    g_w1h[i] = *(unsigned int*)&h;
}

// ================= grid build (shared by both bq calls) =====================
__global__ void grid_zero_kernel() {
    int i = blockIdx.x * 1024 + threadIdx.x;
    if (i < NB * NCELL) ((int*)g_cellcnt)[i] = 0;
}

__device__ __forceinline__ int cell_of(float x, float y, float z) {
    int cx = min(NCX - 1, max(0, (int)floorf(x * INV_CS)));
    int cy = min(NCY - 1, max(0, (int)floorf(y * INV_CS)));
    int cz = min(NCZ - 1, max(0, (int)floorf(z * INV_CS)));
    return (cz * NCY + cy) * NCX + cx;
}

__global__ void grid_count_kernel(const float* __restrict__ xyz) {
    int i = blockIdx.x * 256 + threadIdx.x;   // 0..16383
    int b = i >> 13;
    int cell = cell_of(xyz[(size_t)i * 3 + 0], xyz[(size_t)i * 3 + 1], xyz[(size_t)i * 3 + 2]);
    atomicAdd(&g_cellcnt[b][cell], 1);
}

__global__ void grid_prefix_kernel() {     // one block per batch
    __shared__ int sc[1024];
    int b = blockIdx.x, tid = threadIdx.x;
    int v = (tid < NCELL) ? g_cellcnt[b][tid] : 0;
    sc[tid] = v;
    __syncthreads();
    for (int off = 1; off < 1024; off <<= 1) {
        int add = (tid >= off) ? sc[tid - off] : 0;
        __syncthreads();
        sc[tid] += add;
        __syncthreads();
    }
    if (tid < NCELL) {
        int excl = sc[tid] - v;
        g_cellstart[b][tid] = excl;
        g_cellcur[b][tid] = excl;
    }
    if (tid == 0) g_cellstart[b][NCELL] = NPTS;
}

__global__ void grid_scatter_kernel(const float* __restrict__ xyz) {
    int i = blockIdx.x * 256 + threadIdx.x;
    int b = i >> 13, il = i & (NPTS - 1);
    float x = xyz[(size_t)i * 3 + 0];
    float y = xyz[(size_t)i * 3 + 1];
    float z = xyz[(size_t)i * 3 + 2];
    int cell = cell_of(x, y, z);
    int pos = atomicAdd(&g_cellcur[b][cell], 1);
    g_cellxyzw[b][pos] = make_float4(x, y, z, __int_as_float(il));
}

// ======= ball query via grid: one wave/query, register candidates, =========
// ======= threshold-selection of NS smallest. Chunked cell scan      =========
// ======= (ncell<=512) + T<=1024 so large deform radii don't fall    =========
// ======= back to the 8192-point full scan.                          =========
template <int NS>
__launch_bounds__(256, 8)
__global__ void bq_grid_kernel(const float* __restrict__ xyz, const float* __restrict__ newxyz) {
    __shared__ int s_epos[4][1024];   // 16 KB
    int tid = threadIdx.x, wv = tid >> 6, lane = tid & 63;
    int q = blockIdx.x * 4 + wv;
    int b = q >> 12;
    float qx = newxyz[q * 3 + 0], qy = newxyz[q * 3 + 1], qz = newxyz[q * 3 + 2];
    float r = (NS == SP) ? RADIUS_C : g_rroi[q >> 6];
    float r2 = r * r;
    int* idx_out   = (NS == SP) ? g_idx_p   : g_idx_d;
    int* empty_out = (NS == SP) ? g_empty_p : g_empty_d;

    float rp = r + 1e-4f;                 // cell-range padding (fp safety)
    int xlo = max(0, min(NCX - 1, (int)floorf((qx - rp) * INV_CS)));
    int xhi = max(0, min(NCX - 1, (int)floorf((qx + rp) * INV_CS)));
    int ylo = max(0, min(NCY - 1, (int)floorf((qy - rp) * INV_CS)));
    int yhi = max(0, min(NCY - 1, (int)floorf((qy + rp) * INV_CS)));
    int zlo = max(0, min(NCZ - 1, (int)floorf((qz - rp) * INV_CS)));
    int zhi = max(0, min(NCZ - 1, (int)floorf((qz + rp) * INV_CS)));
    int nx = xhi - xlo + 1, ny = yhi - ylo + 1, nz = zhi - zlo + 1;
    int ncell = nx * ny * nz;

    // phase A: chunked cell enumeration (64 cells per pass)
    int T = 0;
    bool fb = (ncell > 512);
    if (!fb) {
        for (int c0 = 0; c0 < ncell; c0 += 64) {
            int ci = c0 + lane;
            int cstart = 0, ccnt = 0;
            if (ci < ncell) {
                int cx = xlo + (ci % nx);
                int t1 = ci / nx;
                int cy = ylo + (t1 % ny);
                int cz = zlo + (t1 / ny);
                int cell = (cz * NCY + cy) * NCX + cx;
                cstart = g_cellstart[b][cell];
                ccnt = g_cellstart[b][cell + 1] - cstart;
            }
            int incl = ccnt;
#pragma unroll
            for (int off = 1; off < 64; off <<= 1) {
                int n = __shfl_up(incl, off, 64);
                if (lane >= off) incl += n;
            }
            int chunkT = __shfl(incl, 63, 64);
            int pre = T + incl - ccnt;
            if (T + chunkT <= 1024) {
                for (int k = 0; k < ccnt; ++k) s_epos[wv][pre + k] = cstart + k;
            }
            T += chunkT;
        }
        if (T > 1024) fb = true;
    }

    if (fb) {   // rare: enormous radius/candidate set — original ordered scan
        const float* xb = xyz + (size_t)b * NPTS * 3;
        int cnt2 = 0, first_idx = 0;
        for (int g = 0; g < NPTS / 64 && cnt2 < NS; ++g) {
            int p = (g << 6) + lane;
            float dx = qx - xb[3 * p + 0];
            float dy = qy - xb[3 * p + 1];
            float dz = qz - xb[3 * p + 2];
            bool valid = (dx * dx + dy * dy + dz * dz) < r2;
            unsigned long long mask = __ballot(valid);
            if (cnt2 == 0 && mask) first_idx = (g << 6) + (int)__builtin_ctzll(mask);
            int pos = cnt2 + __popcll(mask & ((1ull << lane) - 1ull));
            if (valid && pos < NS) idx_out[q * NS + pos] = p;
            cnt2 += (int)__popcll(mask);
        }
        if (cnt2 == 0) {
            if (lane < NS) idx_out[q * NS + lane] = 0;
            if (lane == 0) empty_out[q] = 1;
        } else {
            int filled = cnt2 < NS ? cnt2 : NS;
            if (lane >= filled && lane < NS) idx_out[q * NS + lane] = first_idx;
            if (lane == 0) empty_out[q] = 0;
        }
        return;
    }
    __asm__ volatile("s_waitcnt lgkmcnt(0)" ::: "memory");

    // phase B: lane = candidate slot; 16 register slots; 1 packed load each
    int p[16];
#pragma unroll
    for (int k = 0; k < 16; ++k) {
        int t = k * 64 + lane;
        int pk = 0x7FFFFFFF;
        if (t < T) {
            int e = s_epos[wv][t];
            float4 v = g_cellxyzw[b][e];
            float dx = qx - v.x, dy = qy - v.y, dz = qz - v.z;
            if (dx * dx + dy * dy + dz * dz < r2) pk = __float_as_int(v.w);
        }
        p[k] = pk;
    }

    // phase C: wave stats
    int lcnt = 0, lmin = 0x7FFFFFFF;
#pragma unroll
    for (int k = 0; k < 16; ++k) {
        if (p[k] != 0x7FFFFFFF) { ++lcnt; lmin = min(lmin, p[k]); }
    }
    int cnt = lcnt, fidx = lmin;
#pragma unroll
    for (int off = 1; off < 64; off <<= 1) {
        cnt += __shfl_xor(cnt, off, 64);
        fidx = min(fidx, __shfl_xor(fidx, off, 64));
    }
    if (cnt == 0) {
        if (lane < NS) idx_out[q * NS + lane] = 0;
        if (lane == 0) empty_out[q] = 1;
        return;
    }
    // threshold = smallest m with #(p < m) >= NS  (indices distinct -> exact NS)
    int thr = 0x7FFFFFFF;
    if (cnt > NS) {
        int lo = 0, hi = NPTS;
        while (lo < hi) {
            int mid = (lo + hi) >> 1;
            int c = 0;
#pragma unroll
            for (int k = 0; k < 16; ++k) c += (p[k] < mid) ? 1 : 0;
#pragma unroll
            for (int off = 1; off < 64; off <<= 1) c += __shfl_xor(c, off, 64);
            if (c >= NS) hi = mid; else lo = mid + 1;
        }
        thr = lo;
    }
    // write qualifying slots at wave-prefix positions (order irrelevant:
    // downstream BN sums / max-pools are order-invariant)
    int qc = 0;
#pragma unroll
    for (int k = 0; k < 16; ++k) qc += (p[k] < thr) ? 1 : 0;
    int qincl = qc;
#pragma unroll
    for (int off = 1; off < 64; off <<= 1) {
        int n = __shfl_up(qincl, off, 64);
        if (lane >= off) qincl += n;
    }
    int pos = qincl - qc;
#pragma unroll
    for (int k = 0; k < 16; ++k) {
        if (p[k] < thr) {
            if (pos < NS) idx_out[q * NS + pos] = p[k];
            ++pos;
        }
    }
    if (lane >= cnt && lane < NS) idx_out[q * NS + lane] = fidx;   // pads
    if (lane == 0) empty_out[q] = 0;
}

// ============ 3-pass MLP =====================================================
// PASS A: gather -> L0 -> store x0 (fp32 for p-branch, fp16 for f-branch) + stats
template <int NS, int CH, bool HALF>
__launch_bounds__(128, 4)
__global__ void mlp_passA_kernel(const float* __restrict__ xyz, const float* __restrict__ feats,
                                 const float* __restrict__ newxyz, const float* __restrict__ W0,
                                 void* __restrict__ xout_) {
    constexpr int GSTR = 37;        // gather row stride (35 used)
    constexpr int SST  = CH + 2;    // stats/store transpose stride
    __shared__ float buf[128 * GSTR];
    __shared__ float ls[128], lq[128];
    int tid = threadIdx.x;
    int rowbase = blockIdx.x * 128;
    int row = rowbase + tid;
    int q = row / NS, b = q >> 12;
    const int* idx_arr = (NS == SP) ? g_idx_p : g_idx_d;
    const int* emp_arr = (NS == SP) ? g_empty_p : g_empty_d;
    {
        float* dst = &buf[tid * GSTR];
        if (emp_arr[q]) {
#pragma unroll
            for (int c = 0; c < 35; ++c) dst[c] = 0.f;
        } else {
            int idx = idx_arr[row];
            const float* xp = xyz + (size_t)b * NPTS * 3 + idx * 3;
            dst[0] = xp[0] - newxyz[q * 3 + 0];
            dst[1] = xp[1] - newxyz[q * 3 + 1];
            dst[2] = xp[2] - newxyz[q * 3 + 2];
            const float4* fp = (const float4*)(feats + (size_t)b * NPTS * CIN + (size_t)idx * CIN);
#pragma unroll
            for (int j = 0; j < 8; ++j) {
                float4 v = fp[j];
                dst[3 + 4 * j + 0] = v.x; dst[3 + 4 * j + 1] = v.y;
                dst[3 + 4 * j + 2] = v.z; dst[3 + 4 * j + 3] = v.w;
            }
        }
    }
    // L0 from own LDS row (no barrier needed)
    float acc[CH];
#pragma unroll
    for (int ch = 0; ch < CH; ++ch) acc[ch] = 0.f;
    {
        const float* inrow = &buf[tid * GSTR];
        for (int c = 0; c < 35; ++c) {
            float h = inrow[c];
#pragma unroll
            for (int ch = 0; ch < CH; ++ch) acc[ch] = fmaf(h, W0[c * CH + ch], acc[ch]);
        }
    }
    // stats (fp32, pre-rounding) + coalesced store via chunked LDS transpose
    float* xf = (float*)xout_;
    __half* xh = (__half*)xout_;
    float sum = 0.f, sq = 0.f;
#pragma unroll
    for (int p = 0; p < 2; ++p) {
        __syncthreads();
        if ((tid >> 6) == p) {
            float* srow = &buf[(tid & 63) * SST];
#pragma unroll
            for (int ch = 0; ch < CH; ++ch) srow[ch] = acc[ch];
        }
        __syncthreads();
        if (CH == 64) {
            int ch = tid & 63, rg = tid >> 6;
            for (int r = 0; r < 32; ++r) {
                float v = buf[(rg * 32 + r) * SST + ch];
                size_t o = (size_t)(rowbase + p * 64 + rg * 32 + r) * CH + ch;
                if (HALF) xh[o] = __float2half_rn(v); else xf[o] = v;
                sum += v; sq += v * v;
            }
        } else {
            int ch = tid & 31, rg = tid >> 5;
            for (int r = 0; r < 16; ++r) {
                float v = buf[(rg * 16 + r) * SST + ch];
                size_t o = (size_t)(rowbase + p * 64 + rg * 16 + r) * CH + ch;
                if (HALF) xh[o] = __float2half_rn(v); else xf[o] = v;
                sum += v; sq += v * v;
            }
        }
    }
    ls[tid] = sum; lq[tid] = sq;
    __syncthreads();
    if (CH == 64) {
        if (tid < 64) {
            g_psT[tid * 2048 + blockIdx.x] = ls[tid] + ls[64 + tid];
            g_pqT[tid * 2048 + blockIdx.x] = lq[tid] + lq[64 + tid];
        }
    } else {
        if (tid < 32) {
            g_psT[tid * 2048 + blockIdx.x] = ls[tid] + ls[32 + tid] + ls[64 + tid] + ls[96 + tid];
            g_pqT[tid * 2048 + blockIdx.x] = lq[tid] + lq[32 + tid] + lq[64 + tid] + lq[96 + tid];
        }
    }
}

// PASS B (p-branch, fp32): stream x0p -> BN0+ReLU -> L1 -> store x1p + stats
template <int NS, int CH>
__launch_bounds__(128, 4)
__global__ void mlp_passB_kernel(const float* __restrict__ W1, const float* __restrict__ xin,
                                 float* __restrict__ xout, int bn0) {
    constexpr int HSTR = 33;
    constexpr int SST  = CH + 2;
    __shared__ float buf[128 * 37];
    __shared__ float ls[128], lq[128];
    int tid = threadIdx.x;
    int rowbase = blockIdx.x * 128;
    const float* sc0 = g_bnscale[bn0];
    const float* sh0 = g_bnshift[bn0];
    float acc2[CH];
#pragma unroll
    for (int ch = 0; ch < CH; ++ch) acc2[ch] = 0.f;
    const float4* src = (const float4*)xin;
#pragma unroll
    for (int hc = 0; hc < CH / 32; ++hc) {
        if (hc) __syncthreads();
#pragma unroll
        for (int k = 0; k < 8; ++k) {
            int o4 = tid + k * 128;       // 0..1023
            int rloc = o4 >> 3, j = o4 & 7;
            int c = 4 * j, gc = hc * 32 + c;
            float4 v = src[(size_t)(rowbase + rloc) * (CH / 4) + hc * 8 + j];
            float* d = &buf[rloc * HSTR + c];
            d[0] = fmaxf(fmaf(v.x, sc0[gc + 0], sh0[gc + 0]), 0.f);
            d[1] = fmaxf(fmaf(v.y, sc0[gc + 1], sh0[gc + 1]), 0.f);
            d[2] = fmaxf(fmaf(v.z, sc0[gc + 2], sh0[gc + 2]), 0.f);
            d[3] = fmaxf(fmaf(v.w, sc0[gc + 3], sh0[gc + 3]), 0.f);
        }
        __syncthreads();
        const float* hrow = &buf[tid * HSTR];
        for (int c = 0; c < 32; ++c) {
            float h = hrow[c];
#pragma unroll
            for (int ch = 0; ch < CH; ++ch)
                acc2[ch] = fmaf(h, W1[(hc * 32 + c) * CH + ch], acc2[ch]);
        }
    }
    float sum = 0.f, sq = 0.f;
#pragma unroll
    for (int p = 0; p < 2; ++p) {
        __syncthreads();
        if ((tid >> 6) == p) {
            float* srow = &buf[(tid & 63) * SST];
#pragma unroll
            for (int ch = 0; ch < CH; ++ch) srow[ch] = acc2[ch];
        }
        __syncthreads();
        int ch = tid & 31, rg = tid >> 5;
        for (int r = 0; r < 16; ++r) {
            float v = buf[(rg * 16 + r) * SST + ch];
            xout[(size_t)(rowbase + p * 64 + rg * 16 + r) * CH + ch] = v;
            sum += v; sq += v * v;
        }
    }
    ls[tid] = sum; lq[tid] = sq;
    __syncthreads();
    if (tid < 32) {
        g_psT[tid * 2048 + blockIdx.x] = ls[tid] + ls[32 + tid] + ls[64 + tid] + ls[96 + tid];
        g_pqT[tid * 2048 + blockIdx.x] = lq[tid] + lq[32 + tid] + lq[64 + tid] + lq[96 + tid];
    }
}

// PASS B (f-branch, fp16 in/out): BN+ReLU packed to half2 in LDS (stride 37
// uints -> conflict-free ds_read_b32), fully-unrolled v_dot2_f32_f16 inner
// loop vs pre-packed W1 pairs, direct per-thread 128-B row stores,
// LDS transpose retained for stats only.
__launch_bounds__(128, 4)
__global__ void mlp_fB_kernel(const __half* __restrict__ xin, __half* __restrict__ xout) {
    __shared__ unsigned int hp[128 * 37];   // 18.9 KB; also reused (float view) for stats
    __shared__ float ls[128], lq[128];
    int tid = threadIdx.x;
    int rowbase = blockIdx.x * 128;
    const float* sc0 = g_bnscale[2];
    const float* sh0 = g_bnshift[2];
    // load: 1024 float4 coalesced; BN0+ReLU; pack half2 -> LDS rows
    {
        const float4* src = (const float4*)xin;
#pragma unroll
        for (int k = 0; k < 8; ++k) {
            int o4 = tid + k * 128;       // 0..1023
            int rloc = o4 >> 3, j = o4 & 7;
            float4 v = src[(size_t)(rowbase + rloc) * 8 + j];
            const __half2* ph = (const __half2*)&v;   // 4 half2 pairs
            unsigned int* d = &hp[rloc * 37 + 4 * j];
#pragma unroll
            for (int m = 0; m < 4; ++m) {
                float2 f = __half22float2(ph[m]);
                int gc = 8 * j + 2 * m;
                float a = fmaxf(fmaf(f.x, sc0[gc + 0], sh0[gc + 0]), 0.f);
                float bb = fmaxf(fmaf(f.y, sc0[gc + 1], sh0[gc + 1]), 0.f);
                __half2 hh = __floats2half2_rn(a, bb);
                d[m] = *(unsigned int*)&hh;
            }
        }
    }
    __syncthreads();
    float acc2[CF];
#pragma unroll
    for (int ch = 0; ch < CF; ++ch) acc2[ch] = 0.f;
    {
        const unsigned int* hrow = &hp[tid * 37];
#pragma unroll
        for (int c2 = 0; c2 < 32; ++c2) {
            unsigned int h2 = hrow[c2];
#pragma unroll
            for (int ch = 0; ch < CF; ++ch)
                acc2[ch] = fdot2f(h2, g_w1h[ch * 32 + c2], acc2[ch]);
        }
    }
    // direct coalesced-chunk store: thread owns row -> 128 B via 8x uint4
    {
        unsigned int orow[32];
#pragma unroll
        for (int m = 0; m < 32; ++m) {
            __half2 hh = __floats2half2_rn(acc2[2 * m], acc2[2 * m + 1]);
            orow[m] = *(unsigned int*)&hh;
        }
        uint4* dst = (uint4*)(xout + (size_t)(rowbase + tid) * CF);
#pragma unroll
        for (int m = 0; m < 8; ++m)
            dst[m] = make_uint4(orow[4 * m], orow[4 * m + 1], orow[4 * m + 2], orow[4 * m + 3]);
    }
    // stats via LDS transpose (read-only now)
    float* fview = (float*)hp;              // [64][66] fits in 18.9 KB
    float sum = 0.f, sq = 0.f;
#pragma unroll
    for (int p = 0; p < 2; ++p) {
        __syncthreads();
        if ((tid >> 6) == p) {
            float* srow = &fview[(tid & 63) * 66];
#pragma unroll
            for (int ch = 0; ch < CF; ++ch) srow[ch] = acc2[ch];
        }
        __syncthreads();
        int ch = tid & 63, rg = tid >> 6;
        for (int r = 0; r < 32; ++r) {
            float v = fview[(rg * 32 + r) * 66 + ch];
            sum += v; sq += v * v;
        }
    }
    ls[tid] = sum; lq[tid] = sq;
    __syncthreads();
    if (tid < 64) {
        g_psT[tid * 2048 + blockIdx.x] = ls[tid] + ls[64 + tid];
        g_pqT[tid * 2048 + blockIdx.x] = lq[tid] + lq[64 + tid];
    }
}

// PASS C deform: stream x1f (fp16), BN1+ReLU, sigmoid weight, max over 32 -> out
__global__ void passC_f_kernel(const float* __restrict__ xyz, const float* __restrict__ newxyz,
                               const float* __restrict__ td, const __half* __restrict__ xin,
                               float* __restrict__ out) {
    __shared__ float lw[64];
    int tid = threadIdx.x;
    int qpair = blockIdx.x * 2;
    if (tid < 64) {
        int ql = tid >> 5, s = tid & 31;
        int q = qpair + ql;
        float wv = 0.f;
        if (!g_empty_d[q]) {
            int idx = g_idx_d[q * SD + s];
            int b = q >> 12;
            float dx = xyz[(size_t)b * NPTS * 3 + idx * 3 + 0] - newxyz[q * 3 + 0];
            float dy = xyz[(size_t)b * NPTS * 3 + idx * 3 + 1] - newxyz[q * 3 + 1];
            float dz = xyz[(size_t)b * NPTS * 3 + idx * 3 + 2] - newxyz[q * 3 + 2];
            float dist = sqrtf(dx * dx + dy * dy + dz * dz);
            float rq = g_rroi[q >> 6];
            wv = 1.f / (1.f + expf(-(rq - dist) / td[0]));
        }
        lw[tid] = wv;
    }
    __syncthreads();
    int ql = tid >> 6, ch = tid & 63;
    int q = qpair + ql;
    float sc = g_bnscale[3][ch], sh = g_bnshift[3][ch];
    float m = 0.f;
    for (int s = 0; s < SD; ++s) {
        float v = __half2float(xin[((size_t)q * SD + s) * CF + ch]);
        m = fmaxf(m, lw[ql * 32 + s] * fmaxf(fmaf(v, sc, sh), 0.f));
    }
    out[MTOT * 3 + (size_t)q * CF + ch] = m;
}

// PASS C pred (fp32): stream x1p, BN1+ReLU, max over 16, dot with fcw -> g_pdot
__global__ void passC_p_kernel(const float* __restrict__ fcw, const float* __restrict__ xin) {
    int tid = threadIdx.x;
    int q = blockIdx.x * 8 + (tid >> 5);
    int ch = tid & 31;
    float sc = g_bnscale[1][ch], sh = g_bnshift[1][ch];
    float m = 0.f;
    for (int s = 0; s < SP; ++s) {
        float v = xin[(size_t)(q * SP + s) * CP + ch] * sc + sh;
        m = fmaxf(m, fmaxf(v, 0.f));
    }
    float pd = m * fcw[(q & 63) * CP + ch];
    for (int off = 16; off > 0; off >>= 1) pd += __shfl_down(pd, off, 32);
    if (ch == 0) g_pdot[q] = pd;
}

// -------- BN stats finalize: one block per channel, coalesced, tree-reduce --
__global__ void finalize_kernel(const float* __restrict__ gamma, const float* __restrict__ beta,
                                float n, int layer, int nblocks) {
    __shared__ double l_s[256], l_q[256];
    int ch = blockIdx.x, tid = threadIdx.x;
    double s = 0, q = 0;
    for (int i = tid; i < nblocks; i += 256) { s += g_psT[ch * 2048 + i]; q += g_pqT[ch * 2048 + i]; }
    l_s[tid] = s; l_q[tid] = q; __syncthreads();
    for (int off = 128; off > 0; off >>= 1) {
        if (tid < off) { l_s[tid] += l_s[tid + off]; l_q[tid] += l_q[tid + off]; }
        __syncthreads();
    }
    if (tid == 0) {
        double mu = l_s[0] / (double)n;
        double var = l_q[0] / (double)n - mu * mu;
        if (var < 0) var = 0;
        double sc = (double)gamma[ch] / sqrt(var + 1e-5);
        g_bnscale[layer][ch] = (float)sc;
        g_bnshift[layer][ch] = (float)((double)beta[ch] - mu * sc);
    }
}

// ---------------- per-roi fc reduce -> deform radius -----------------------
__global__ void roi_r_kernel(const float* __restrict__ roif, const float* __restrict__ fcw,
                             const float* __restrict__ fcb) {
    int tid = threadIdx.x;
    int roi = blockIdx.x * 4 + (tid >> 6);
    int lane = tid & 63;
    float acc = g_pdot[roi * 64 + lane]
              + roif[roi * 128 + lane]      * fcw[2048 + lane]
              + roif[roi * 128 + 64 + lane] * fcw[2048 + 64 + lane];
    for (int off = 32; off > 0; off >>= 1) acc += __shfl_down(acc, off, 64);
    if (lane == 0) {
        float res = acc + fcb[0];
        g_rroi[roi] = fmaxf(res / DIV_COEF_C + RADIUS_C, MIN_R_C);
    }
}

extern "C" void kernel_launch(void* const* d_in, const int* in_sizes, int n_in,
                              void* d_out, int out_size, void* d_ws, size_t ws_size,
                              hipStream_t stream) {
    const float* xyz   = (const float*)d_in[0];
    const float* feats = (const float*)d_in[1];
    const float* rois  = (const float*)d_in[2];
    const float* roif  = (const float*)d_in[3];
    const float* td    = (const float*)d_in[4];
    const float* pw0 = (const float*)d_in[5];
    const float* pg0 = (const float*)d_in[6];
    const float* pb0 = (const float*)d_in[7];
    const float* pw1 = (const float*)d_in[8];
    const float* pg1 = (const float*)d_in[9];
    const float* pb1 = (const float*)d_in[10];
    const float* fw0 = (const float*)d_in[11];
    const float* fg0 = (const float*)d_in[12];
    const float* fb0 = (const float*)d_in[13];
    const float* fw1 = (const float*)d_in[14];
    const float* fg1 = (const float*)d_in[15];
    const float* fb1 = (const float*)d_in[16];
    const float* fcw = (const float*)d_in[17];
    const float* fcb = (const float*)d_in[18];
    float* out = (float*)d_out;

    void* xa; hipGetSymbolAddress(&xa, HIP_SYMBOL(g_xa));
    void* xb; hipGetSymbolAddress(&xb, HIP_SYMBOL(g_xb));

    copy_xyz_kernel<<<96, 256, 0, stream>>>(rois, out);
    prep_w1_kernel<<<8, 256, 0, stream>>>(fw1);

    // grid build (once; reused by both ball queries; order irrelevant)
    grid_zero_kernel<<<2, 1024, 0, stream>>>();
    grid_count_kernel<<<64, 256, 0, stream>>>(xyz);
    grid_prefix_kernel<<<2, 1024, 0, stream>>>();
    grid_scatter_kernel<<<64, 256, 0, stream>>>(xyz);

    // pred branch (16 samples, 32 ch, all fp32)
    bq_grid_kernel<SP><<<MTOT / 4, 256, 0, stream>>>(xyz, rois);
    mlp_passA_kernel<SP, CP, false><<<1024, 128, 0, stream>>>(xyz, feats, rois, pw0, xa);
    finalize_kernel<<<CP, 256, 0, stream>>>(pg0, pb0, (float)(MTOT * SP), 0, 1024);
    mlp_passB_kernel<SP, CP><<<1024, 128, 0, stream>>>(pw1, (const float*)xa, (float*)xb, 0);
    finalize_kernel<<<CP, 256, 0, stream>>>(pg1, pb1, (float)(MTOT * SP), 1, 1024);
    passC_p_kernel<<<MTOT / 8, 256, 0, stream>>>(fcw, (const float*)xb);
    roi_r_kernel<<<NROI / 4, 256, 0, stream>>>(roif, fcw, fcb);

    // deform branch (32 samples, 64 ch, fp16 intermediates)
    bq_grid_kernel<SD><<<MTOT / 4, 256, 0, stream>>>(xyz, rois);
    mlp_passA_kernel<SD, CF, true><<<2048, 128, 0, stream>>>(xyz, feats, rois, fw0, xa);
    finalize_kernel<<<CF, 256, 0, stream>>>(fg0, fb0, (float)(MTOT * SD), 2, 2048);
    mlp_fB_kernel<<<2048, 128, 0, stream>>>((const __half*)xa, (__half*)xb);
    finalize_kernel<<<CF, 256, 0, stream>>>(fg1, fb1, (float)(MTOT * SD), 3, 2048);
    passC_f_kernel<<<MTOT / 2, 128, 0, stream>>>(xyz, rois, td, (const __half*)xb, out);
}